// Round 1
// baseline (50.274 us; speedup 1.0000x reference)
//
#include <hip/hip_runtime.h>
#include <math.h>

// B=128, N=512, D=1024, C=512
// s: (128,1536) f32   a=s[:, :512], z=s[:, 512:]
// out: (128,1536) f32  da=out[:, :512], dz=out[:, 512:]
// Strategy: k_gemm writes c = a@Wl+bl into the dz region of out; k_dz
// (1 block per batch) reads that row into LDS, then overwrites with dz.

__global__ __launch_bounds__(256) void k_gemm(
    const float* __restrict__ s, const float* __restrict__ ctx,
    const float* __restrict__ Wa, const float* __restrict__ Wc,
    const float* __restrict__ ba, const float* __restrict__ Wl,
    const float* __restrict__ bl, float* __restrict__ out)
{
    const int col = blockIdx.x * 256 + threadIdx.x;   // 0..1535 (uniform path per block)
    const int b0  = blockIdx.y * 4;                   // 4 batches per thread
    const float* srow = s + (size_t)b0 * 1536;

    if (col < 512) {
        // da = tanh(a@Wa + ctx@Wc + ba)
        float acc0 = 0.f, acc1 = 0.f, acc2 = 0.f, acc3 = 0.f;
        const float* crow = ctx + (size_t)b0 * 512;
        #pragma unroll 8
        for (int k = 0; k < 512; ++k) {
            float w = Wa[k * 512 + col];
            acc0 = fmaf(srow[k],            w, acc0);
            acc1 = fmaf(srow[1536 + k],     w, acc1);
            acc2 = fmaf(srow[2 * 1536 + k], w, acc2);
            acc3 = fmaf(srow[3 * 1536 + k], w, acc3);
        }
        #pragma unroll 8
        for (int k = 0; k < 512; ++k) {
            float w = Wc[k * 512 + col];
            acc0 = fmaf(crow[k],           w, acc0);
            acc1 = fmaf(crow[512 + k],     w, acc1);
            acc2 = fmaf(crow[2 * 512 + k], w, acc2);
            acc3 = fmaf(crow[3 * 512 + k], w, acc3);
        }
        const float bias = ba[col];
        out[(size_t)(b0 + 0) * 1536 + col] = tanhf(acc0 + bias);
        out[(size_t)(b0 + 1) * 1536 + col] = tanhf(acc1 + bias);
        out[(size_t)(b0 + 2) * 1536 + col] = tanhf(acc2 + bias);
        out[(size_t)(b0 + 3) * 1536 + col] = tanhf(acc3 + bias);
    } else {
        // c = a@Wl + bl  -> staged into dz region of out
        const int c2 = col - 512;                     // 0..1023
        float acc0 = 0.f, acc1 = 0.f, acc2 = 0.f, acc3 = 0.f;
        #pragma unroll 8
        for (int k = 0; k < 512; ++k) {
            float w = Wl[k * 1024 + c2];
            acc0 = fmaf(srow[k],            w, acc0);
            acc1 = fmaf(srow[1536 + k],     w, acc1);
            acc2 = fmaf(srow[2 * 1536 + k], w, acc2);
            acc3 = fmaf(srow[3 * 1536 + k], w, acc3);
        }
        const float bias = bl[c2];
        out[(size_t)(b0 + 0) * 1536 + 512 + c2] = acc0 + bias;
        out[(size_t)(b0 + 1) * 1536 + 512 + c2] = acc1 + bias;
        out[(size_t)(b0 + 2) * 1536 + 512 + c2] = acc2 + bias;
        out[(size_t)(b0 + 3) * 1536 + 512 + c2] = acc3 + bias;
    }
}

// dz[b,i] = sum_k c[b,k] * z[b,(i+k)%1024]
// 512 threads: h = t>>8 selects K-half (koff = 512h), g = t&255 -> 4 consecutive
// outputs i0 = 4g. Rolling float4 window over duplicated z.
__global__ __launch_bounds__(512) void k_dz(const float* __restrict__ s, float* out)
{
    __shared__ float zdup[2064];   // 1024 duplicated + pad (float4-safe prefetch)
    __shared__ float cc[1024];
    __shared__ float part[1024];

    const int b = blockIdx.x;
    const int t = threadIdx.x;

    const float4* s4 = (const float4*)(s + (size_t)b * 1536 + 512);
    const float4* o4 = (const float4*)(out + (size_t)b * 1536 + 512);

    if (t < 256) {
        float4 v = s4[t];
        ((float4*)zdup)[t]       = v;
        ((float4*)zdup)[256 + t] = v;
    } else {
        ((float4*)cc)[t - 256] = o4[t - 256];   // c staged by k_gemm
    }
    __syncthreads();

    const int g = t & 255;        // output group: i0 = 4g
    const int h = t >> 8;         // K-half
    const int base4 = g + 128 * h;            // (i0 + koff)/4
    const float4* z4 = (const float4*)zdup;
    const float4* c4 = ((const float4*)cc) + 128 * h;

    float4 w0 = z4[base4];
    float4 w1 = z4[base4 + 1];
    float a0 = 0.f, a1 = 0.f, a2 = 0.f, a3 = 0.f;

    #pragma unroll 4
    for (int m = 0; m < 128; ++m) {
        const float4 cv = c4[m];
        const float4 wn = z4[base4 + m + 2];  // prefetch next window quad
        a0 = fmaf(cv.x, w0.x, a0); a0 = fmaf(cv.y, w0.y, a0);
        a0 = fmaf(cv.z, w0.z, a0); a0 = fmaf(cv.w, w0.w, a0);
        a1 = fmaf(cv.x, w0.y, a1); a1 = fmaf(cv.y, w0.z, a1);
        a1 = fmaf(cv.z, w0.w, a1); a1 = fmaf(cv.w, w1.x, a1);
        a2 = fmaf(cv.x, w0.z, a2); a2 = fmaf(cv.y, w0.w, a2);
        a2 = fmaf(cv.z, w1.x, a2); a2 = fmaf(cv.w, w1.y, a2);
        a3 = fmaf(cv.x, w0.w, a3); a3 = fmaf(cv.y, w1.x, a3);
        a3 = fmaf(cv.z, w1.y, a3); a3 = fmaf(cv.w, w1.z, a3);
        w0 = w1; w1 = wn;
    }

    if (h == 1) {
        ((float4*)part)[g] = make_float4(a0, a1, a2, a3);
    }
    __syncthreads();
    if (h == 0) {
        const float4 p = ((float4*)part)[g];
        float4 r;
        r.x = a0 + p.x; r.y = a1 + p.y; r.z = a2 + p.z; r.w = a3 + p.w;
        ((float4*)(out + (size_t)b * 1536 + 512))[g] = r;
    }
}

extern "C" void kernel_launch(void* const* d_in, const int* in_sizes, int n_in,
                              void* d_out, int out_size, void* d_ws, size_t ws_size,
                              hipStream_t stream) {
    // inputs: 0=t, 1=s, 2=context, 3=Wa, 4=Wc, 5=ba, 6=Wl, 7=bl
    const float* s   = (const float*)d_in[1];
    const float* ctx = (const float*)d_in[2];
    const float* Wa  = (const float*)d_in[3];
    const float* Wc  = (const float*)d_in[4];
    const float* ba  = (const float*)d_in[5];
    const float* Wl  = (const float*)d_in[6];
    const float* bl  = (const float*)d_in[7];
    float* out = (float*)d_out;

    k_gemm<<<dim3(6, 32), 256, 0, stream>>>(s, ctx, Wa, Wc, ba, Wl, bl, out);
    k_dz<<<128, 512, 0, stream>>>(s, out);
}

// Round 2
// 24.673 us; speedup vs baseline: 2.0376x; 2.0376x over previous
//
#include <hip/hip_runtime.h>
#include <math.h>

// B=128, N=512, D=1024, C=512
// s: (128,1536) f32, a=s[:,:512], z=s[:,512:]; out: (128,1536) f32 = [da | dz]
// GEMM1: da = tanh([a|ctx](128x1024) @ [Wa;Wc](1024x512) + ba)   -> MFMA bf16
// GEMM2: c  = a(128x512) @ Wl(512x1024) + bl                      -> MFMA bf16
// dz[b,i] = sum_k c[b,k] * z[b,(i+k)%1024]                        -> fp32 VALU

typedef float f32x4 __attribute__((ext_vector_type(4)));
typedef __bf16 bf16x8 __attribute__((ext_vector_type(8)));

__device__ __forceinline__ unsigned short f2bf(float f) {
    unsigned u = __float_as_uint(f);
    u += 0x7fffu + ((u >> 16) & 1u);   // RNE
    return (unsigned short)(u >> 16);
}

// ---------------------------------------------------------------------------
// Fused MFMA GEMM kernel. 96 blocks x 512 threads (8 waves).
// Block: 64(M) x 32(N) output tile; wave w handles K-chunk = Ktot/8,
// staged 32-k at a time into wave-private LDS (f32->bf16 on the fly),
// 8 MFMA (4 m-frags x 2 n-frags) per 32-k step. LDS partial reduce at end.
// A and B frags both use permuted k-slots sigma(kq,j) = {4kq+j, 16+4kq+j}
// (same bijection on both operands => correct sum).
// ---------------------------------------------------------------------------
__global__ __launch_bounds__(512) void k_gemm(
    const float* __restrict__ s, const float* __restrict__ ctx,
    const float* __restrict__ Wa, const float* __restrict__ Wc,
    const float* __restrict__ ba, const float* __restrict__ Wl,
    const float* __restrict__ bl, float* __restrict__ out,
    float* __restrict__ cdst, int cstride, int coff)
{
    // A: [8 waves][64 rows][40 ushort (32 bf16 + pad)]  = 40KB
    // B: [8 waves][32 rows][40 ushort]                  = 20KB  (rows = N-cols, k-minor)
    // red (aliases A/B after sync): [4][64][36] f32     = 36.9KB
    __shared__ __align__(16) unsigned short sm[30720];

    const int tid = threadIdx.x;
    const int w = tid >> 6;
    const int l = tid & 63;
    const int bidx = blockIdx.x;
    const int bt = (bidx < 32) ? 0 : 1;
    int nt, mt;
    if (bt == 0) { nt = bidx & 15; mt = bidx >> 4; }
    else { int b2 = bidx - 32; nt = b2 & 31; mt = b2 >> 5; }
    const int M0 = mt * 64, N0 = nt * 32;
    const int nst = (bt == 0) ? 4 : 2;    // 32-k stages per wave

    const int Abase = w * 2560;            // ushort offsets
    const int Bbase = 20480 + w * 1280;
    const int lk = l & 15;
    const int kq = l >> 4;

    f32x4 acc[4][2];
    #pragma unroll
    for (int fm = 0; fm < 4; ++fm)
        #pragma unroll
        for (int nf = 0; nf < 2; ++nf)
            acc[fm][nf] = (f32x4){0.f, 0.f, 0.f, 0.f};

    for (int st = 0; st < nst; ++st) {
        const int kb = (w * nst + st) * 32;

        // ---- stage A: lane l loads row (M0+l), 32 k, converts, writes permuted
        {
            const float* src;
            if (bt == 0)
                src = (kb < 512) ? (s + (size_t)(M0 + l) * 1536 + kb)
                                 : (ctx + (size_t)(M0 + l) * 512 + (kb - 512));
            else
                src = s + (size_t)(M0 + l) * 1536 + kb;
            const float4* s4 = reinterpret_cast<const float4*>(src);
            float4 f[8];
            #pragma unroll
            for (int j = 0; j < 8; ++j) f[j] = s4[j];
            #pragma unroll
            for (int c = 0; c < 4; ++c) {
                #pragma unroll
                for (int h = 0; h < 2; ++h) {
                    float4 v = f[c + 4 * h];
                    uint2 d;
                    d.x = (unsigned)f2bf(v.x) | ((unsigned)f2bf(v.y) << 16);
                    d.y = (unsigned)f2bf(v.z) | ((unsigned)f2bf(v.w) << 16);
                    *reinterpret_cast<uint2*>(&sm[Abase + l * 40 + c * 8 + h * 4]) = d;
                }
            }
        }
        // ---- stage B (transpose): lane: k = l&31, nh = l>>5 -> 16 cols
        {
            const int k31 = l & 31, nh = l >> 5;
            const int kg = kb + k31;
            const float* wsrc;
            if (bt == 0)
                wsrc = (kb < 512) ? (Wa + (size_t)kg * 512 + N0 + 16 * nh)
                                  : (Wc + (size_t)(kg - 512) * 512 + N0 + 16 * nh);
            else
                wsrc = Wl + (size_t)kg * 1024 + N0 + 16 * nh;
            const float4* w4 = reinterpret_cast<const float4*>(wsrc);
            const int posu = ((k31 & 15) >> 2) * 8 + (k31 >> 4) * 4 + (k31 & 3);
            #pragma unroll
            for (int q = 0; q < 4; ++q) {
                float4 v = w4[q];
                const int r0 = 16 * nh + q * 4;
                sm[Bbase + (size_t)(r0 + 0) * 40 + posu] = f2bf(v.x);
                sm[Bbase + (size_t)(r0 + 1) * 40 + posu] = f2bf(v.y);
                sm[Bbase + (size_t)(r0 + 2) * 40 + posu] = f2bf(v.z);
                sm[Bbase + (size_t)(r0 + 3) * 40 + posu] = f2bf(v.w);
            }
        }
        // ---- 8 MFMA on this 32-k step (wave-private LDS, no barrier needed)
        bf16x8 bf[2];
        #pragma unroll
        for (int nf = 0; nf < 2; ++nf) {
            uint4 bv = *reinterpret_cast<const uint4*>(&sm[Bbase + (16 * nf + lk) * 40 + kq * 8]);
            bf[nf] = __builtin_bit_cast(bf16x8, bv);
        }
        #pragma unroll
        for (int fm = 0; fm < 4; ++fm) {
            uint4 av = *reinterpret_cast<const uint4*>(&sm[Abase + (16 * fm + lk) * 40 + kq * 8]);
            bf16x8 af = __builtin_bit_cast(bf16x8, av);
            acc[fm][0] = __builtin_amdgcn_mfma_f32_16x16x32_bf16(af, bf[0], acc[fm][0], 0, 0, 0);
            acc[fm][1] = __builtin_amdgcn_mfma_f32_16x16x32_bf16(af, bf[1], acc[fm][1], 0, 0, 0);
        }
    }

    // ---- cross-wave reduce of 8 partial 64x32 tiles via LDS (2 rounds)
    __syncthreads();
    float* red = reinterpret_cast<float*>(sm);   // [4][64][36]
    if (w < 4) {
        #pragma unroll
        for (int fm = 0; fm < 4; ++fm)
            #pragma unroll
            for (int nf = 0; nf < 2; ++nf)
                #pragma unroll
                for (int r = 0; r < 4; ++r)
                    red[w * 2304 + (16 * fm + 4 * kq + r) * 36 + 16 * nf + lk] = acc[fm][nf][r];
    }
    __syncthreads();
    if (w >= 4) {
        #pragma unroll
        for (int fm = 0; fm < 4; ++fm)
            #pragma unroll
            for (int nf = 0; nf < 2; ++nf)
                #pragma unroll
                for (int r = 0; r < 4; ++r)
                    red[(w - 4) * 2304 + (16 * fm + 4 * kq + r) * 36 + 16 * nf + lk] += acc[fm][nf][r];
    }
    __syncthreads();

    // ---- epilogue: thread -> (row m, 4 cols)
    {
        const int m = tid >> 3, nq = tid & 7;
        const int base = m * 36 + nq * 4;
        float4 r0 = *reinterpret_cast<const float4*>(&red[base]);
        float4 r1 = *reinterpret_cast<const float4*>(&red[2304 + base]);
        float4 r2 = *reinterpret_cast<const float4*>(&red[4608 + base]);
        float4 r3 = *reinterpret_cast<const float4*>(&red[6912 + base]);
        float s0 = r0.x + r1.x + r2.x + r3.x;
        float s1 = r0.y + r1.y + r2.y + r3.y;
        float s2 = r0.z + r1.z + r2.z + r3.z;
        float s3 = r0.w + r1.w + r2.w + r3.w;
        const int col = N0 + nq * 4;
        if (bt == 0) {
            float4 bv = *reinterpret_cast<const float4*>(&ba[col]);
            float4 o;
            o.x = tanhf(s0 + bv.x); o.y = tanhf(s1 + bv.y);
            o.z = tanhf(s2 + bv.z); o.w = tanhf(s3 + bv.w);
            *reinterpret_cast<float4*>(&out[(size_t)(M0 + m) * 1536 + col]) = o;
        } else {
            float4 bv = *reinterpret_cast<const float4*>(&bl[col]);
            float4 o;
            o.x = s0 + bv.x; o.y = s1 + bv.y; o.z = s2 + bv.z; o.w = s3 + bv.w;
            *reinterpret_cast<float4*>(&cdst[(size_t)(M0 + m) * cstride + coff + col]) = o;
        }
    }
}

// ---------------------------------------------------------------------------
// dz variant A (c in workspace): 256 blocks (batch, i-half) x 512 threads.
// thread: g=t&63, kq=t>>6 -> outputs {I0+4g+i} u {I0+256+4g+i}, K-chunk 128.
// ---------------------------------------------------------------------------
__global__ __launch_bounds__(512) void k_dzA(const float* __restrict__ s,
                                             const float* __restrict__ csrc,
                                             float* __restrict__ out)
{
    __shared__ __align__(16) float zdup[2064];
    __shared__ float part[8 * 512];
    const int b = blockIdx.x >> 1;
    const int ih = blockIdx.x & 1;
    const int t = threadIdx.x;
    if (t < 256) {
        float4 v = reinterpret_cast<const float4*>(s + (size_t)b * 1536 + 512)[t];
        reinterpret_cast<float4*>(zdup)[t] = v;
        reinterpret_cast<float4*>(zdup)[256 + t] = v;
    }
    __syncthreads();
    const int g = t & 63;
    const int kq = __builtin_amdgcn_readfirstlane(t >> 6);
    const float4* c4 = reinterpret_cast<const float4*>(csrc + (size_t)b * 1024 + kq * 128);
    const int I0 = ih * 512;
    const float4* z4 = reinterpret_cast<const float4*>(zdup);
    const int baseA = (I0 >> 2) + g + kq * 32;
    const int baseB = baseA + 64;
    float4 a0 = z4[baseA], a1 = z4[baseA + 1];
    float4 b0 = z4[baseB], b1 = z4[baseB + 1];
    float accA[4] = {0.f, 0.f, 0.f, 0.f}, accB[4] = {0.f, 0.f, 0.f, 0.f};
    #pragma unroll 4
    for (int m = 0; m < 32; ++m) {
        float4 cv = c4[m];
        float4 a2 = z4[baseA + m + 2];
        float4 b2 = z4[baseB + m + 2];
        accA[0] = fmaf(cv.x, a0.x, accA[0]); accA[0] = fmaf(cv.y, a0.y, accA[0]);
        accA[0] = fmaf(cv.z, a0.z, accA[0]); accA[0] = fmaf(cv.w, a0.w, accA[0]);
        accA[1] = fmaf(cv.x, a0.y, accA[1]); accA[1] = fmaf(cv.y, a0.z, accA[1]);
        accA[1] = fmaf(cv.z, a0.w, accA[1]); accA[1] = fmaf(cv.w, a1.x, accA[1]);
        accA[2] = fmaf(cv.x, a0.z, accA[2]); accA[2] = fmaf(cv.y, a0.w, accA[2]);
        accA[2] = fmaf(cv.z, a1.x, accA[2]); accA[2] = fmaf(cv.w, a1.y, accA[2]);
        accA[3] = fmaf(cv.x, a0.w, accA[3]); accA[3] = fmaf(cv.y, a1.x, accA[3]);
        accA[3] = fmaf(cv.z, a1.y, accA[3]); accA[3] = fmaf(cv.w, a1.z, accA[3]);
        accB[0] = fmaf(cv.x, b0.x, accB[0]); accB[0] = fmaf(cv.y, b0.y, accB[0]);
        accB[0] = fmaf(cv.z, b0.z, accB[0]); accB[0] = fmaf(cv.w, b0.w, accB[0]);
        accB[1] = fmaf(cv.x, b0.y, accB[1]); accB[1] = fmaf(cv.y, b0.z, accB[1]);
        accB[1] = fmaf(cv.z, b0.w, accB[1]); accB[1] = fmaf(cv.w, b1.x, accB[1]);
        accB[2] = fmaf(cv.x, b0.z, accB[2]); accB[2] = fmaf(cv.y, b0.w, accB[2]);
        accB[2] = fmaf(cv.z, b1.x, accB[2]); accB[2] = fmaf(cv.w, b1.y, accB[2]);
        accB[3] = fmaf(cv.x, b0.w, accB[3]); accB[3] = fmaf(cv.y, b1.x, accB[3]);
        accB[3] = fmaf(cv.z, b1.y, accB[3]); accB[3] = fmaf(cv.w, b1.z, accB[3]);
        a0 = a1; a1 = a2; b0 = b1; b1 = b2;
    }
    *reinterpret_cast<float4*>(&part[kq * 512 + 4 * g]) = make_float4(accA[0], accA[1], accA[2], accA[3]);
    *reinterpret_cast<float4*>(&part[kq * 512 + 256 + 4 * g]) = make_float4(accB[0], accB[1], accB[2], accB[3]);
    __syncthreads();
    float sum = 0.f;
    #pragma unroll
    for (int q = 0; q < 8; ++q) sum += part[q * 512 + t];
    out[(size_t)b * 1536 + 512 + I0 + t] = sum;
}

// ---------------------------------------------------------------------------
// dz variant B (no workspace): 128 blocks x 512 threads; c (staged by k_gemm
// into out's dz region) is copied to LDS before any write -> race-free.
// ---------------------------------------------------------------------------
__global__ __launch_bounds__(512) void k_dzB(const float* __restrict__ s,
                                             float* __restrict__ out)
{
    __shared__ __align__(16) float zdup[2064];
    __shared__ __align__(16) float cl[1024];
    __shared__ float part[8 * 1024];
    const int b = blockIdx.x;
    const int t = threadIdx.x;
    if (t < 256) {
        float4 v = reinterpret_cast<const float4*>(s + (size_t)b * 1536 + 512)[t];
        reinterpret_cast<float4*>(zdup)[t] = v;
        reinterpret_cast<float4*>(zdup)[256 + t] = v;
    } else {
        int i = t - 256;
        reinterpret_cast<float4*>(cl)[i] =
            reinterpret_cast<const float4*>(out + (size_t)b * 1536 + 512)[i];
    }
    __syncthreads();
    const int g = t & 63;
    const int kq = t >> 6;
    const float4* c4 = reinterpret_cast<const float4*>(cl) + kq * 32;
    const float4* z4 = reinterpret_cast<const float4*>(zdup);
    float acc[4][4] = {};
    float4 w0[4], w1[4];
    int base[4];
    #pragma unroll
    for (int q = 0; q < 4; ++q) {
        base[q] = 64 * q + g + kq * 32;
        w0[q] = z4[base[q]];
        w1[q] = z4[base[q] + 1];
    }
    #pragma unroll 2
    for (int m = 0; m < 32; ++m) {
        float4 cv = c4[m];
        #pragma unroll
        for (int q = 0; q < 4; ++q) {
            float4 w2 = z4[base[q] + m + 2];
            acc[q][0] = fmaf(cv.x, w0[q].x, acc[q][0]); acc[q][0] = fmaf(cv.y, w0[q].y, acc[q][0]);
            acc[q][0] = fmaf(cv.z, w0[q].z, acc[q][0]); acc[q][0] = fmaf(cv.w, w0[q].w, acc[q][0]);
            acc[q][1] = fmaf(cv.x, w0[q].y, acc[q][1]); acc[q][1] = fmaf(cv.y, w0[q].z, acc[q][1]);
            acc[q][1] = fmaf(cv.z, w0[q].w, acc[q][1]); acc[q][1] = fmaf(cv.w, w1[q].x, acc[q][1]);
            acc[q][2] = fmaf(cv.x, w0[q].z, acc[q][2]); acc[q][2] = fmaf(cv.y, w0[q].w, acc[q][2]);
            acc[q][2] = fmaf(cv.z, w1[q].x, acc[q][2]); acc[q][2] = fmaf(cv.w, w1[q].y, acc[q][2]);
            acc[q][3] = fmaf(cv.x, w0[q].w, acc[q][3]); acc[q][3] = fmaf(cv.y, w1[q].x, acc[q][3]);
            acc[q][3] = fmaf(cv.z, w1[q].y, acc[q][3]); acc[q][3] = fmaf(cv.w, w1[q].z, acc[q][3]);
            w0[q] = w1[q]; w1[q] = w2;
        }
    }
    #pragma unroll
    for (int q = 0; q < 4; ++q)
        *reinterpret_cast<float4*>(&part[kq * 1024 + 256 * q + 4 * g]) =
            make_float4(acc[q][0], acc[q][1], acc[q][2], acc[q][3]);
    __syncthreads();
    #pragma unroll
    for (int rep = 0; rep < 2; ++rep) {
        const int o = t + rep * 512;
        float sum = 0.f;
        #pragma unroll
        for (int q = 0; q < 8; ++q) sum += part[q * 1024 + o];
        out[(size_t)b * 1536 + 512 + o] = sum;
    }
}

extern "C" void kernel_launch(void* const* d_in, const int* in_sizes, int n_in,
                              void* d_out, int out_size, void* d_ws, size_t ws_size,
                              hipStream_t stream) {
    // inputs: 0=t, 1=s, 2=context, 3=Wa, 4=Wc, 5=ba, 6=Wl, 7=bl
    const float* s   = (const float*)d_in[1];
    const float* ctx = (const float*)d_in[2];
    const float* Wa  = (const float*)d_in[3];
    const float* Wc  = (const float*)d_in[4];
    const float* ba  = (const float*)d_in[5];
    const float* Wl  = (const float*)d_in[6];
    const float* bl  = (const float*)d_in[7];
    float* out = (float*)d_out;

    const bool use_ws = ws_size >= (size_t)(128 * 1024 * sizeof(float));
    float* cdst = use_ws ? (float*)d_ws : out;
    const int cstride = use_ws ? 1024 : 1536;
    const int coff = use_ws ? 0 : 512;

    k_gemm<<<96, 512, 0, stream>>>(s, ctx, Wa, Wc, ba, Wl, bl, out, cdst, cstride, coff);
    if (use_ws)
        k_dzA<<<256, 512, 0, stream>>>(s, (const float*)d_ws, out);
    else
        k_dzB<<<128, 512, 0, stream>>>(s, out);
}

// Round 3
// 20.237 us; speedup vs baseline: 2.4843x; 1.2192x over previous
//
#include <hip/hip_runtime.h>
#include <math.h>

// B=128, N=512, D=1024, C=512
// s: (128,1536) f32, a=s[:,:512], z=s[:,512:]; out: (128,1536) f32 = [da | dz]
// GEMM1: da = tanh([a|ctx](128x1024) @ [Wa;Wc](1024x512) + ba)
// GEMM2: c  = a(128x512) @ Wl(512x1024) + bl
// dz[b,i] = sum_k c[b,k] * z[b,(i+k)%1024]
//
// Pipeline: k_pack builds fragment-packed bf16 operands in d_ws (A serves both
// GEMMs: k-steps 0..15 are the `a` columns), k_mm is an LDS-free MFMA GEMM
// (1 dwordx4 load per fragment, K-split 8 + LDS reduce), k_dz is fp32 VALU.
//
// Both A and B fragments use the same k-slot bijection sigma(kq,j):
//   j<4 -> k = 32*ks + 4*kq + j ; j>=4 -> k = 32*ks + 16 + 4*kq + (j-4)
// (same permutation on both operands => exact GEMM; validated round 2).

typedef float f32x4 __attribute__((ext_vector_type(4)));
typedef __bf16 bf16x8 __attribute__((ext_vector_type(8)));

__device__ __forceinline__ unsigned f2bf(float f) {
    unsigned u = __float_as_uint(f);
    u += 0x7fffu + ((u >> 16) & 1u);   // RNE
    return u >> 16;
}

// ws layout (bytes):
//   Apack  @ 0        : 8mt x 32ks x 64l x 8 bf16 = 256 KB
//   Bpack1 @ 262144   : 32nt x 32ks x 64l x 8     = 1 MB   ([Wa;Wc])
//   Bpack2 @ 1310720  : 64nt x 16ks x 64l x 8     = 1 MB   (Wl)
//   c      @ 2359296  : 128 x 1024 f32            = 512 KB
#define APACK_OFF_U16 0
#define BP1_OFF_U16   131072
#define BP2_OFF_U16   655360
#define C_OFF_BYTES   2359296

// ---------------------------------------------------------------------------
// Pack kernel: 288 blocks x 512 threads.
//   blocks [0,32):    Apack   (mt,ks,l)
//   blocks [32,160):  Bpack1  (nt,ks,l)
//   blocks [160,288): Bpack2  (nt,ks,l)
// ---------------------------------------------------------------------------
__global__ __launch_bounds__(512) void k_pack(
    const float* __restrict__ s, const float* __restrict__ ctx,
    const float* __restrict__ Wa, const float* __restrict__ Wc,
    const float* __restrict__ Wl, unsigned short* __restrict__ ws16)
{
    const int bid = blockIdx.x;
    const int t = threadIdx.x;
    const int l = t & 63;
    const int lk = l & 15, kq = l >> 4;

    if (bid < 32) {
        // ---- Apack: idx = (mt*32+ks)*64 + l
        const int idx = bid * 512 + t;
        const int ks = (idx >> 6) & 31;
        const int mt = idx >> 11;
        const int row = mt * 16 + lk;
        const int kb = ks * 32;
        const int k0 = kb + 4 * kq;          // j<4 quad
        const int k1 = k0 + 16;              // j>=4 quad (same source region)
        float4 v0, v1;
        if (kb < 512) {
            v0 = *reinterpret_cast<const float4*>(s + (size_t)row * 1536 + k0);
            v1 = *reinterpret_cast<const float4*>(s + (size_t)row * 1536 + k1);
        } else {
            v0 = *reinterpret_cast<const float4*>(ctx + (size_t)row * 512 + (k0 - 512));
            v1 = *reinterpret_cast<const float4*>(ctx + (size_t)row * 512 + (k1 - 512));
        }
        uint4 d;
        d.x = f2bf(v0.x) | (f2bf(v0.y) << 16);
        d.y = f2bf(v0.z) | (f2bf(v0.w) << 16);
        d.z = f2bf(v1.x) | (f2bf(v1.y) << 16);
        d.w = f2bf(v1.z) | (f2bf(v1.w) << 16);
        *reinterpret_cast<uint4*>(ws16 + APACK_OFF_U16 + (size_t)idx * 8) = d;
    } else if (bid < 160) {
        // ---- Bpack1 ([Wa;Wc]): idx = (nt*32+ks)*64 + l, col = nt*16+lk
        const int idx = (bid - 32) * 512 + t;
        const int ks = (idx >> 6) & 31;
        const int nt = idx >> 11;
        const int col = nt * 16 + lk;
        const int kb = ks * 32;
        const float* __restrict__ base;   // whole 32-k step is in one region
        int krel;
        if (kb < 512) { base = Wa; krel = kb; }
        else          { base = Wc; krel = kb - 512; }
        float f[8];
        #pragma unroll
        for (int j = 0; j < 4; ++j)
            f[j] = base[(size_t)(krel + 4 * kq + j) * 512 + col];
        #pragma unroll
        for (int j = 0; j < 4; ++j)
            f[4 + j] = base[(size_t)(krel + 16 + 4 * kq + j) * 512 + col];
        uint4 d;
        d.x = f2bf(f[0]) | (f2bf(f[1]) << 16);
        d.y = f2bf(f[2]) | (f2bf(f[3]) << 16);
        d.z = f2bf(f[4]) | (f2bf(f[5]) << 16);
        d.w = f2bf(f[6]) | (f2bf(f[7]) << 16);
        *reinterpret_cast<uint4*>(ws16 + BP1_OFF_U16 + (size_t)idx * 8) = d;
    } else {
        // ---- Bpack2 (Wl): idx = (nt*16+ks)*64 + l, col = nt*16+lk (0..1023)
        const int idx = (bid - 160) * 512 + t;
        const int ks = (idx >> 6) & 15;
        const int nt = idx >> 10;
        const int col = nt * 16 + lk;
        const int kb = ks * 32;
        float f[8];
        #pragma unroll
        for (int j = 0; j < 4; ++j)
            f[j] = Wl[(size_t)(kb + 4 * kq + j) * 1024 + col];
        #pragma unroll
        for (int j = 0; j < 4; ++j)
            f[4 + j] = Wl[(size_t)(kb + 16 + 4 * kq + j) * 1024 + col];
        uint4 d;
        d.x = f2bf(f[0]) | (f2bf(f[1]) << 16);
        d.y = f2bf(f[2]) | (f2bf(f[3]) << 16);
        d.z = f2bf(f[4]) | (f2bf(f[5]) << 16);
        d.w = f2bf(f[6]) | (f2bf(f[7]) << 16);
        *reinterpret_cast<uint4*>(ws16 + BP2_OFF_U16 + (size_t)idx * 8) = d;
    }
}

// ---------------------------------------------------------------------------
// LDS-free MFMA GEMM: 384 blocks x 512 threads (8 waves).
// Block owns a 16x32 output tile; wave w = K-chunk w (K-split 8).
//   blocks [0,128):   GEMM1 (da, tanh epilogue), KS=32, 4 ks/wave
//   blocks [128,384): GEMM2 (c),                 KS=16, 2 ks/wave
// Per ks: 1 A dwordx4 + 2 B dwordx4 + 2 MFMA. LDS reduce of 8 partials.
// ---------------------------------------------------------------------------
__global__ __launch_bounds__(512) void k_mm(
    const unsigned short* __restrict__ ws16,
    const float* __restrict__ ba, const float* __restrict__ bl,
    float* __restrict__ out, float* __restrict__ c)
{
    __shared__ float red[4][16 * 33];   // +1 pad: kq-stride 132 -> banks spread

    const int t = threadIdx.x, w = t >> 6, l = t & 63;
    const int lk = l & 15, kq = l >> 4;
    const int bid = blockIdx.x;

    const bool g1 = bid < 128;
    int mt, ntp, KS, nks;
    const unsigned short* bsrc;
    if (g1) { mt = bid >> 4; ntp = bid & 15; KS = 32; nks = 4; bsrc = ws16 + BP1_OFF_U16; }
    else { int b2 = bid - 128; mt = b2 >> 5; ntp = b2 & 31; KS = 16; nks = 2; bsrc = ws16 + BP2_OFF_U16; }
    const unsigned short* apack = ws16 + APACK_OFF_U16;

    f32x4 acc0 = (f32x4){0.f, 0.f, 0.f, 0.f};
    f32x4 acc1 = (f32x4){0.f, 0.f, 0.f, 0.f};

    const int ks0 = w * nks;
    #pragma unroll 4
    for (int i = 0; i < nks; ++i) {
        const int ks = ks0 + i;
        uint4 av = *reinterpret_cast<const uint4*>(apack + ((size_t)(mt * 32 + ks) * 64 + l) * 8);
        uint4 bv0 = *reinterpret_cast<const uint4*>(bsrc + ((size_t)((ntp * 2 + 0) * KS + ks) * 64 + l) * 8);
        uint4 bv1 = *reinterpret_cast<const uint4*>(bsrc + ((size_t)((ntp * 2 + 1) * KS + ks) * 64 + l) * 8);
        bf16x8 af = __builtin_bit_cast(bf16x8, av);
        acc0 = __builtin_amdgcn_mfma_f32_16x16x32_bf16(af, __builtin_bit_cast(bf16x8, bv0), acc0, 0, 0, 0);
        acc1 = __builtin_amdgcn_mfma_f32_16x16x32_bf16(af, __builtin_bit_cast(bf16x8, bv1), acc1, 0, 0, 0);
    }

    // ---- cross-wave K reduce (C/D map: m = kq*4 + reg, n16 = lk)
    if (w < 4) {
        #pragma unroll
        for (int r = 0; r < 4; ++r) {
            red[w][(kq * 4 + r) * 33 + lk]      = acc0[r];
            red[w][(kq * 4 + r) * 33 + 16 + lk] = acc1[r];
        }
    }
    __syncthreads();
    if (w >= 4) {
        #pragma unroll
        for (int r = 0; r < 4; ++r) {
            red[w - 4][(kq * 4 + r) * 33 + lk]      += acc0[r];
            red[w - 4][(kq * 4 + r) * 33 + 16 + lk] += acc1[r];
        }
    }
    __syncthreads();

    // ---- epilogue: thread t -> (m = t>>5, n = t&31)
    const int m = t >> 5, n = t & 31;
    const int o = m * 33 + n;
    const float v = red[0][o] + red[1][o] + red[2][o] + red[3][o];
    const int row = mt * 16 + m;
    const int col = ntp * 32 + n;
    if (g1)
        out[(size_t)row * 1536 + col] = tanhf(v + ba[col]);
    else
        c[(size_t)row * 1024 + col] = v + bl[col];
}

// ---------------------------------------------------------------------------
// dz: 256 blocks (batch, i-half) x 512 threads, fp32 VALU, rolling window.
// thread: g=t&63, kq=t>>6 -> outputs {I0+4g..} u {I0+256+4g..}, K-chunk 128.
// ---------------------------------------------------------------------------
__global__ __launch_bounds__(512) void k_dz(const float* __restrict__ s,
                                            const float* __restrict__ csrc,
                                            float* __restrict__ out)
{
    __shared__ __align__(16) float zdup[2064];
    __shared__ float part[8 * 512];
    const int b = blockIdx.x >> 1;
    const int ih = blockIdx.x & 1;
    const int t = threadIdx.x;
    if (t < 256) {
        float4 v = reinterpret_cast<const float4*>(s + (size_t)b * 1536 + 512)[t];
        reinterpret_cast<float4*>(zdup)[t] = v;
        reinterpret_cast<float4*>(zdup)[256 + t] = v;
    }
    __syncthreads();
    const int g = t & 63;
    const int kq = __builtin_amdgcn_readfirstlane(t >> 6);
    const float4* c4 = reinterpret_cast<const float4*>(csrc + (size_t)b * 1024 + kq * 128);
    const int I0 = ih * 512;
    const float4* z4 = reinterpret_cast<const float4*>(zdup);
    const int baseA = (I0 >> 2) + g + kq * 32;
    const int baseB = baseA + 64;
    float4 a0 = z4[baseA], a1 = z4[baseA + 1];
    float4 b0 = z4[baseB], b1 = z4[baseB + 1];
    float accA[4] = {0.f, 0.f, 0.f, 0.f}, accB[4] = {0.f, 0.f, 0.f, 0.f};
    #pragma unroll 4
    for (int m = 0; m < 32; ++m) {
        float4 cv = c4[m];
        float4 a2 = z4[baseA + m + 2];
        float4 b2 = z4[baseB + m + 2];
        accA[0] = fmaf(cv.x, a0.x, accA[0]); accA[0] = fmaf(cv.y, a0.y, accA[0]);
        accA[0] = fmaf(cv.z, a0.z, accA[0]); accA[0] = fmaf(cv.w, a0.w, accA[0]);
        accA[1] = fmaf(cv.x, a0.y, accA[1]); accA[1] = fmaf(cv.y, a0.z, accA[1]);
        accA[1] = fmaf(cv.z, a0.w, accA[1]); accA[1] = fmaf(cv.w, a1.x, accA[1]);
        accA[2] = fmaf(cv.x, a0.z, accA[2]); accA[2] = fmaf(cv.y, a0.w, accA[2]);
        accA[2] = fmaf(cv.z, a1.x, accA[2]); accA[2] = fmaf(cv.w, a1.y, accA[2]);
        accA[3] = fmaf(cv.x, a0.w, accA[3]); accA[3] = fmaf(cv.y, a1.x, accA[3]);
        accA[3] = fmaf(cv.z, a1.y, accA[3]); accA[3] = fmaf(cv.w, a1.z, accA[3]);
        accB[0] = fmaf(cv.x, b0.x, accB[0]); accB[0] = fmaf(cv.y, b0.y, accB[0]);
        accB[0] = fmaf(cv.z, b0.z, accB[0]); accB[0] = fmaf(cv.w, b0.w, accB[0]);
        accB[1] = fmaf(cv.x, b0.y, accB[1]); accB[1] = fmaf(cv.y, b0.z, accB[1]);
        accB[1] = fmaf(cv.z, b0.w, accB[1]); accB[1] = fmaf(cv.w, b1.x, accB[1]);
        accB[2] = fmaf(cv.x, b0.z, accB[2]); accB[2] = fmaf(cv.y, b0.w, accB[2]);
        accB[2] = fmaf(cv.z, b1.x, accB[2]); accB[2] = fmaf(cv.w, b1.y, accB[2]);
        accB[3] = fmaf(cv.x, b0.w, accB[3]); accB[3] = fmaf(cv.y, b1.x, accB[3]);
        accB[3] = fmaf(cv.z, b1.y, accB[3]); accB[3] = fmaf(cv.w, b1.z, accB[3]);
        a0 = a1; a1 = a2; b0 = b1; b1 = b2;
    }
    *reinterpret_cast<float4*>(&part[kq * 512 + 4 * g]) = make_float4(accA[0], accA[1], accA[2], accA[3]);
    *reinterpret_cast<float4*>(&part[kq * 512 + 256 + 4 * g]) = make_float4(accB[0], accB[1], accB[2], accB[3]);
    __syncthreads();
    float sum = 0.f;
    #pragma unroll
    for (int q = 0; q < 8; ++q) sum += part[q * 512 + t];
    out[(size_t)b * 1536 + 512 + I0 + t] = sum;
}

extern "C" void kernel_launch(void* const* d_in, const int* in_sizes, int n_in,
                              void* d_out, int out_size, void* d_ws, size_t ws_size,
                              hipStream_t stream) {
    // inputs: 0=t, 1=s, 2=context, 3=Wa, 4=Wc, 5=ba, 6=Wl, 7=bl
    const float* s   = (const float*)d_in[1];
    const float* ctx = (const float*)d_in[2];
    const float* Wa  = (const float*)d_in[3];
    const float* Wc  = (const float*)d_in[4];
    const float* ba  = (const float*)d_in[5];
    const float* Wl  = (const float*)d_in[6];
    const float* bl  = (const float*)d_in[7];
    float* out = (float*)d_out;

    unsigned short* ws16 = (unsigned short*)d_ws;
    float* c = (float*)((char*)d_ws + C_OFF_BYTES);

    k_pack<<<288, 512, 0, stream>>>(s, ctx, Wa, Wc, Wl, ws16);
    k_mm<<<384, 512, 0, stream>>>(ws16, ba, bl, out, c);
    k_dz<<<256, 512, 0, stream>>>(s, c, out);
}